// Round 5
// baseline (640.893 us; speedup 1.0000x reference)
//
#include <hip/hip_runtime.h>
#include <hip/hip_bf16.h>

#define N_TOK 2048
#define DMODEL 1024
#define NEXP 8
#define FFDIM 4096
#define NMAX 2048
#define ROWS 4096

#define BM 128
#define BN 128
#define BK 64
#define MT_MAX 16
#define KSPL 4

typedef __attribute__((ext_vector_type(8))) short s16x8;
typedef __attribute__((ext_vector_type(4))) float f32x4;

__device__ __forceinline__ float bf2f(ushort u) {
    union { uint i; float f; } x; x.i = ((uint)u) << 16; return x.f;
}
__device__ __forceinline__ ushort f2bf(float f) {
    union { float f; uint i; } x; x.f = f;
    uint r = x.i + 0x7fffu + ((x.i >> 16) & 1u);
    return (ushort)(r >> 16);
}

__device__ __forceinline__ void gl_lds16(const void* g, void* l) {
    __builtin_amdgcn_global_load_lds(
        (const __attribute__((address_space(1))) unsigned int*)g,
        (__attribute__((address_space(3))) unsigned int*)l, 16, 0, 0);
}

__device__ __forceinline__ float block_sum(float v, float* s4) {
    #pragma unroll
    for (int off = 32; off; off >>= 1) v += __shfl_down(v, off);
    __syncthreads();
    if ((threadIdx.x & 63) == 0) s4[threadIdx.x >> 6] = v;
    __syncthreads();
    return s4[0] + s4[1] + s4[2] + s4[3];
}

// ---------------- Router ----------------
__global__ __launch_bounds__(256)
void router_kernel(const float* __restrict__ x, const float* __restrict__ gate_w,
                   ushort* __restrict__ norm, float* __restrict__ scores,
                   int* __restrict__ cnt, int* __restrict__ lists,
                   int4* __restrict__ info, float2* __restrict__ gpair) {
    __shared__ float s4[4];
    const int n = blockIdx.x, tid = threadIdx.x;
    const float* xr = x + (size_t)n * DMODEL;
    float4 v = *(const float4*)(xr + tid * 4);

    float tot = block_sum(v.x + v.y + v.z + v.w, s4);
    float mu = tot * (1.0f / DMODEL);
    float d0 = v.x - mu, d1 = v.y - mu, d2 = v.z - mu, d3 = v.w - mu;
    float var = block_sum(d0 * d0 + d1 * d1 + d2 * d2 + d3 * d3, s4) * (1.0f / DMODEL);
    float rstd = rsqrtf(var + 1e-6f);

    ushort nb[4] = { f2bf(d0 * rstd), f2bf(d1 * rstd), f2bf(d2 * rstd), f2bf(d3 * rstd) };
    *(uint2*)(norm + (size_t)n * DMODEL + tid * 4) = *(uint2*)nb;

    float lg[NEXP];
    #pragma unroll
    for (int e = 0; e < NEXP; ++e) {
        float4 g = *(const float4*)(gate_w + (size_t)e * DMODEL + tid * 4);
        lg[e] = v.x * g.x + v.y * g.y + v.z * g.z + v.w * g.w;
    }
    #pragma unroll
    for (int e = 0; e < NEXP; ++e) lg[e] = block_sum(lg[e], s4);

    if (tid == 0) {
        float m = lg[0];
        #pragma unroll
        for (int e = 1; e < NEXP; ++e) m = fmaxf(m, lg[e]);
        float ex[NEXP], Z = 0.f;
        #pragma unroll
        for (int e = 0; e < NEXP; ++e) { ex[e] = expf(lg[e] - m); Z += ex[e]; }
        float inv = 1.0f / Z;
        float sc[NEXP];
        #pragma unroll
        for (int e = 0; e < NEXP; ++e) { sc[e] = ex[e] * inv; scores[n * NEXP + e] = sc[e]; }
        int i1 = 0;
        #pragma unroll
        for (int e = 1; e < NEXP; ++e) if (sc[e] > sc[i1]) i1 = e;
        int i2 = (i1 == 0) ? 1 : 0;
        #pragma unroll
        for (int e = 0; e < NEXP; ++e) if (e != i1 && sc[e] > sc[i2]) i2 = e;
        int s1 = atomicAdd(&cnt[i1], 1);
        lists[i1 * NMAX + s1] = n;
        int s2 = atomicAdd(&cnt[i2], 1);
        lists[i2 * NMAX + s2] = n;
        info[n] = make_int4(i1, s1, i2, s2);
        gpair[n] = make_float2(sc[i1], sc[i2]);
    }
}

// ---------------- Prep: aux loss + exclusive scan ----------------
__global__ __launch_bounds__(256)
void prep_kernel(const float* __restrict__ scores, const int* __restrict__ cnt,
                 int* __restrict__ offs, float* __restrict__ aux_out) {
    __shared__ float s4[4];
    __shared__ float imp[NEXP];
    float part[NEXP] = {};
    for (int i = threadIdx.x; i < N_TOK; i += 256) {
        #pragma unroll
        for (int e = 0; e < NEXP; ++e) part[e] += scores[i * NEXP + e];
    }
    #pragma unroll
    for (int e = 0; e < NEXP; ++e) {
        float s = block_sum(part[e], s4);
        if (threadIdx.x == 0) imp[e] = s;
    }
    __syncthreads();
    if (threadIdx.x == 0) {
        float aux = 0.f; int run = 0;
        #pragma unroll
        for (int e = 0; e < NEXP; ++e) {
            aux += imp[e] * (float)cnt[e];
            offs[e] = run; run += cnt[e];
        }
        aux_out[0] = aux * (float)NEXP / ((float)N_TOK * (float)N_TOK);
    }
}

// ---------------- Gather: A1[row] = norm[token]*ln_g[e] + ln_b[e] ----------------
__global__ __launch_bounds__(256)
void gather_kernel(const ushort* __restrict__ norm, const float* __restrict__ ln_g,
                   const float* __restrict__ ln_b, const int* __restrict__ offs,
                   const int* __restrict__ lists, ushort* __restrict__ A1) {
    const int r = blockIdx.x;
    int e = 0;
    #pragma unroll
    for (int k = 1; k < NEXP; ++k) if (r >= offs[k]) e = k;
    const int slot = r - offs[e];
    const int token = lists[e * NMAX + slot];
    const int t4 = threadIdx.x * 4;
    uint2 nbv = *(const uint2*)(norm + (size_t)token * DMODEL + t4);
    ushort ns[4]; *(uint2*)ns = nbv;
    float4 gv = *(const float4*)(ln_g + (size_t)e * DMODEL + t4);
    float4 bv = *(const float4*)(ln_b + (size_t)e * DMODEL + t4);
    ushort ob[4] = { f2bf(bf2f(ns[0]) * gv.x + bv.x), f2bf(bf2f(ns[1]) * gv.y + bv.y),
                     f2bf(bf2f(ns[2]) * gv.z + bv.z), f2bf(bf2f(ns[3]) * gv.w + bv.w) };
    *(uint2*)(A1 + (size_t)r * DMODEL + t4) = *(uint2*)ob;
}

// ---------------- Grouped GEMM: A(bf16, LDS via gl_lds) x W(f32, direct-to-reg) ------
// W fragments loaded per-lane straight from global f32 one K-step ahead; converted
// with v_cvt_pk_bf16_f32 at use. Barrier waits ONLY the A gl_lds (counted vmcnt(16));
// W loads stay in flight across barriers (T4).
// NOTE: stageA/issueW BOTH take the K-STEP INDEX and scale by BK internally (R4 bug:
// stageA took an element offset at one call site and a step index at another).
template<int KDIM, int NT, int KSPLT, bool RELU>
__global__ __launch_bounds__(256, 2)
void moe_gemm(const ushort* __restrict__ A, const float* __restrict__ W,
              const float* __restrict__ bias, const int* __restrict__ cnt,
              const int* __restrict__ offs, ushort* __restrict__ hout,
              float* __restrict__ yout) {
    __shared__ ushort As[2][BM * BK];
    constexpr int NOUT = NT * BN;

    const int q = (int)gridDim.x >> 3;
    const int logical = ((int)blockIdx.x & 7) * q + ((int)blockIdx.x >> 3);
    const int mt = logical & (MT_MAX - 1);
    int g = logical >> 4;
    const int kb = g & (KSPLT - 1);
    g /= KSPLT;
    const int nt = g % NT;
    const int e = g / NT;
    const int M = cnt[e];
    if (mt * BM >= M) return;
    const int base = offs[e];

    const int tid = threadIdx.x, lane = tid & 63, wave = tid >> 6;
    const int wm = (wave & 1) * 64, wn = (wave >> 1) * 64;
    const int trow = lane >> 3;
    const int scol = ((lane & 7) ^ trow) * 8;   // pre-swizzled A source column

    const ushort* Agb = A + (size_t)(base + mt * BM) * KDIM;
    // per-lane W base: row = e*NOUT + nt*BN + wn + (lane&15), k-chunk (lane>>4)*8
    const float* Wlane = W + ((size_t)e * NOUT + nt * BN + wn + (lane & 15)) * KDIM
                           + (lane >> 4) * 8;

    f32x4 acc[4][4] = {};
    float4 wA[8], wB[8];
    s16x8 bfv[8];

    auto stageA = [&](int step, int b) {      // step = K-step index
        #pragma unroll
        for (int i = 0; i < 4; ++i) {
            int c = wave * 4 + i;
            gl_lds16(Agb + (size_t)(c * 8 + trow) * KDIM + step * BK + scol, &As[b][c * 512]);
        }
    };
    auto issueW = [&](int step) {             // step = K-step index
        #pragma unroll
        for (int f = 0; f < 8; ++f) {
            const int ni = f & 3, kki = f >> 2;
            const float* p = Wlane + (size_t)ni * 16 * KDIM + step * BK + kki * 32;
            wA[f] = *(const float4*)p;
            wB[f] = *(const float4*)(p + 4);
        }
    };
    auto convertW = [&]() {
        #pragma unroll
        for (int f = 0; f < 8; ++f) {
            union { s16x8 v; __hip_bfloat162 h2[4]; } u;
            u.h2[0] = __float22bfloat162_rn(make_float2(wA[f].x, wA[f].y));
            u.h2[1] = __float22bfloat162_rn(make_float2(wA[f].z, wA[f].w));
            u.h2[2] = __float22bfloat162_rn(make_float2(wB[f].x, wB[f].y));
            u.h2[3] = __float22bfloat162_rn(make_float2(wB[f].z, wB[f].w));
            bfv[f] = u.v;
        }
    };
    auto mfma_phase = [&](int b) {
        #pragma unroll
        for (int kki = 0; kki < 2; ++kki) {
            const int cx = (kki * 32 + (lane >> 4) * 8) ^ ((lane & 7) << 3);
            s16x8 af[4];
            #pragma unroll
            for (int mi = 0; mi < 4; ++mi)
                af[mi] = *(const s16x8*)&As[b][(wm + mi * 16 + (lane & 15)) * BK + cx];
            #pragma unroll
            for (int mi = 0; mi < 4; ++mi)
                #pragma unroll
                for (int ni = 0; ni < 4; ++ni)
                    acc[mi][ni] = __builtin_amdgcn_mfma_f32_16x16x32_bf16(
                        af[mi], bfv[kki * 4 + ni], acc[mi][ni], 0, 0, 0);
        }
    };

    const int KS = KDIM / BK / KSPLT;
    const int kt0 = kb * KS;

    stageA(kt0, 0);
    __builtin_amdgcn_sched_barrier(0);
    issueW(kt0);
    __builtin_amdgcn_sched_barrier(0);
    asm volatile("s_waitcnt vmcnt(16)" ::: "memory");  // A gl_lds retired; W in flight
    __builtin_amdgcn_s_barrier();
    __builtin_amdgcn_sched_barrier(0);

    int buf = 0;
    for (int s = 0; s < KS; ++s) {
        convertW();                                   // waits this step's W loads
        if (s + 1 < KS) {
            stageA(kt0 + s + 1, buf ^ 1);             // A gl_lds first (oldest)
            __builtin_amdgcn_sched_barrier(0);
            issueW(kt0 + s + 1);                      // 16 W loads after
        }
        mfma_phase(buf);
        __builtin_amdgcn_sched_barrier(0);
        asm volatile("s_waitcnt vmcnt(16)" ::: "memory");  // waits only the 4 gl_lds
        __builtin_amdgcn_s_barrier();
        __builtin_amdgcn_sched_barrier(0);
        buf ^= 1;
    }

    if (RELU) {
        #pragma unroll
        for (int ni = 0; ni < 4; ++ni) {
            const int nn = nt * BN + wn + ni * 16 + (lane & 15);
            const float bv = bias[(size_t)e * NOUT + nn];
            #pragma unroll
            for (int mi = 0; mi < 4; ++mi)
                #pragma unroll
                for (int r = 0; r < 4; ++r) {
                    const int slot = mt * BM + wm + mi * 16 + ((lane >> 4) << 2) + r;
                    if (slot < M)
                        hout[(size_t)(base + slot) * NOUT + nn] =
                            f2bf(fmaxf(acc[mi][ni][r] + bv, 0.f));
                }
        }
    } else {
        #pragma unroll
        for (int ni = 0; ni < 4; ++ni) {
            const int nn = nt * BN + wn + ni * 16 + (lane & 15);
            #pragma unroll
            for (int mi = 0; mi < 4; ++mi)
                #pragma unroll
                for (int r = 0; r < 4; ++r) {
                    const int slot = mt * BM + wm + mi * 16 + ((lane >> 4) << 2) + r;
                    if (slot < M)
                        yout[((size_t)kb * ROWS + base + slot) * NOUT + nn] = acc[mi][ni][r];
                }
        }
    }
}

// ---------------- Combine: out[n] = sum_e g_e * (sum_kb ypart + b2[e] + x[n]) -------
__global__ __launch_bounds__(256)
void combine_kernel(const float* __restrict__ ypart, const float* __restrict__ b2,
                    const float* __restrict__ x, const int* __restrict__ offs,
                    const int4* __restrict__ info, const float2* __restrict__ gpair,
                    float* __restrict__ out) {
    const int n = blockIdx.x, d = threadIdx.x * 4;
    const int4 ii = info[n];
    const float2 g = gpair[n];
    const int r1 = offs[ii.x] + ii.y, r2 = offs[ii.z] + ii.w;
    f32x4 y1 = {}, y2 = {};
    #pragma unroll
    for (int kb = 0; kb < KSPL; ++kb) {
        y1 += *(const f32x4*)(ypart + ((size_t)kb * ROWS + r1) * DMODEL + d);
        y2 += *(const f32x4*)(ypart + ((size_t)kb * ROWS + r2) * DMODEL + d);
    }
    const f32x4 b21 = *(const f32x4*)(b2 + (size_t)ii.x * DMODEL + d);
    const f32x4 b22 = *(const f32x4*)(b2 + (size_t)ii.z * DMODEL + d);
    const f32x4 xv  = *(const f32x4*)(x + (size_t)n * DMODEL + d);
    f32x4 o = g.x * (y1 + b21 + xv) + g.y * (y2 + b22 + xv);
    *(f32x4*)(out + (size_t)n * DMODEL + d) = o;
}

extern "C" void kernel_launch(void* const* d_in, const int* in_sizes, int n_in,
                              void* d_out, int out_size, void* d_ws, size_t ws_size,
                              hipStream_t stream) {
    const float* x      = (const float*)d_in[0];
    const float* gate_w = (const float*)d_in[1];
    const float* ln_g   = (const float*)d_in[2];
    const float* ln_b   = (const float*)d_in[3];
    const float* w1     = (const float*)d_in[4];
    const float* b1     = (const float*)d_in[5];
    const float* w2     = (const float*)d_in[6];
    const float* b2     = (const float*)d_in[7];
    float* out = (float*)d_out;

    char* w = (char*)d_ws;
    int*    cnt    = (int*)(w + 0);
    int*    offs   = (int*)(w + 64);
    int*    lists  = (int*)(w + 1024);            // 64 KB
    float*  scores = (float*)(w + 66560);         // 64 KB
    int4*   info   = (int4*)(w + 132096);         // 32 KB
    float2* gpair  = (float2*)(w + 164864);       // 16 KB
    ushort* norm   = (ushort*)(w + 181248);       // 4 MB
    ushort* A1     = (ushort*)(w + 4375552);      // 8.4 MB
    ushort* h      = (ushort*)(w + 12764160);     // 33.6 MB
    float*  ypart  = (float*)(w + 46318592);      // 64 MB (KSPL x ROWS x D f32)

    hipMemsetAsync(cnt, 0, 64, stream);

    router_kernel<<<N_TOK, 256, 0, stream>>>(x, gate_w, norm, scores, cnt, lists, info, gpair);
    prep_kernel<<<1, 256, 0, stream>>>(scores, cnt, offs, out + (size_t)N_TOK * DMODEL);
    gather_kernel<<<ROWS, 256, 0, stream>>>(norm, ln_g, ln_b, offs, lists, A1);
    moe_gemm<DMODEL, FFDIM / BN, 1, true><<<(FFDIM / BN) * MT_MAX * NEXP, 256, 0, stream>>>(
        A1, w1, b1, cnt, offs, h, nullptr);
    moe_gemm<FFDIM, DMODEL / BN, KSPL, false><<<(DMODEL / BN) * MT_MAX * NEXP * KSPL, 256, 0, stream>>>(
        h, w2, nullptr, cnt, offs, nullptr, ypart);
    combine_kernel<<<N_TOK, 256, 0, stream>>>(ypart, b2, x, offs, info, gpair, out);
}

// Round 6
// 365.041 us; speedup vs baseline: 1.7557x; 1.7557x over previous
//
#include <hip/hip_runtime.h>
#include <hip/hip_bf16.h>

#define N_TOK 2048
#define DMODEL 1024
#define NEXP 8
#define FFDIM 4096
#define NMAX 2048
#define ROWS 4096

#define BM 128
#define BN 128
#define BK 64
#define MT_MAX 16
#define KSPL 4

typedef __attribute__((ext_vector_type(8))) short s16x8;
typedef __attribute__((ext_vector_type(4))) float f32x4;

__device__ __forceinline__ float bf2f(ushort u) {
    union { uint i; float f; } x; x.i = ((uint)u) << 16; return x.f;
}
__device__ __forceinline__ ushort f2bf(float f) {
    union { float f; uint i; } x; x.f = f;
    uint r = x.i + 0x7fffu + ((x.i >> 16) & 1u);
    return (ushort)(r >> 16);
}

__device__ __forceinline__ void gl_lds16(const void* g, void* l) {
    __builtin_amdgcn_global_load_lds(
        (const __attribute__((address_space(1))) unsigned int*)g,
        (__attribute__((address_space(3))) unsigned int*)l, 16, 0, 0);
}

__device__ __forceinline__ float block_sum(float v, float* s4) {
    #pragma unroll
    for (int off = 32; off; off >>= 1) v += __shfl_down(v, off);
    __syncthreads();
    if ((threadIdx.x & 63) == 0) s4[threadIdx.x >> 6] = v;
    __syncthreads();
    return s4[0] + s4[1] + s4[2] + s4[3];
}

// ---------------- Router ----------------
__global__ __launch_bounds__(256)
void router_kernel(const float* __restrict__ x, const float* __restrict__ gate_w,
                   ushort* __restrict__ norm, float* __restrict__ scores,
                   int* __restrict__ cnt, int* __restrict__ lists,
                   int4* __restrict__ info, float2* __restrict__ gpair) {
    __shared__ float s4[4];
    const int n = blockIdx.x, tid = threadIdx.x;
    const float* xr = x + (size_t)n * DMODEL;
    float4 v = *(const float4*)(xr + tid * 4);

    float tot = block_sum(v.x + v.y + v.z + v.w, s4);
    float mu = tot * (1.0f / DMODEL);
    float d0 = v.x - mu, d1 = v.y - mu, d2 = v.z - mu, d3 = v.w - mu;
    float var = block_sum(d0 * d0 + d1 * d1 + d2 * d2 + d3 * d3, s4) * (1.0f / DMODEL);
    float rstd = rsqrtf(var + 1e-6f);

    ushort nb[4] = { f2bf(d0 * rstd), f2bf(d1 * rstd), f2bf(d2 * rstd), f2bf(d3 * rstd) };
    *(uint2*)(norm + (size_t)n * DMODEL + tid * 4) = *(uint2*)nb;

    float lg[NEXP];
    #pragma unroll
    for (int e = 0; e < NEXP; ++e) {
        float4 g = *(const float4*)(gate_w + (size_t)e * DMODEL + tid * 4);
        lg[e] = v.x * g.x + v.y * g.y + v.z * g.z + v.w * g.w;
    }
    #pragma unroll
    for (int e = 0; e < NEXP; ++e) lg[e] = block_sum(lg[e], s4);

    if (tid == 0) {
        float m = lg[0];
        #pragma unroll
        for (int e = 1; e < NEXP; ++e) m = fmaxf(m, lg[e]);
        float ex[NEXP], Z = 0.f;
        #pragma unroll
        for (int e = 0; e < NEXP; ++e) { ex[e] = expf(lg[e] - m); Z += ex[e]; }
        float inv = 1.0f / Z;
        float sc[NEXP];
        #pragma unroll
        for (int e = 0; e < NEXP; ++e) { sc[e] = ex[e] * inv; scores[n * NEXP + e] = sc[e]; }
        int i1 = 0;
        #pragma unroll
        for (int e = 1; e < NEXP; ++e) if (sc[e] > sc[i1]) i1 = e;
        int i2 = (i1 == 0) ? 1 : 0;
        #pragma unroll
        for (int e = 0; e < NEXP; ++e) if (e != i1 && sc[e] > sc[i2]) i2 = e;
        int s1 = atomicAdd(&cnt[i1], 1);
        lists[i1 * NMAX + s1] = n;
        int s2 = atomicAdd(&cnt[i2], 1);
        lists[i2 * NMAX + s2] = n;
        info[n] = make_int4(i1, s1, i2, s2);
        gpair[n] = make_float2(sc[i1], sc[i2]);
    }
}

// ---------------- Prep: aux loss + exclusive scan ----------------
__global__ __launch_bounds__(256)
void prep_kernel(const float* __restrict__ scores, const int* __restrict__ cnt,
                 int* __restrict__ offs, float* __restrict__ aux_out) {
    __shared__ float s4[4];
    __shared__ float imp[NEXP];
    float part[NEXP] = {};
    for (int i = threadIdx.x; i < N_TOK; i += 256) {
        #pragma unroll
        for (int e = 0; e < NEXP; ++e) part[e] += scores[i * NEXP + e];
    }
    #pragma unroll
    for (int e = 0; e < NEXP; ++e) {
        float s = block_sum(part[e], s4);
        if (threadIdx.x == 0) imp[e] = s;
    }
    __syncthreads();
    if (threadIdx.x == 0) {
        float aux = 0.f; int run = 0;
        #pragma unroll
        for (int e = 0; e < NEXP; ++e) {
            aux += imp[e] * (float)cnt[e];
            offs[e] = run; run += cnt[e];
        }
        aux_out[0] = aux * (float)NEXP / ((float)N_TOK * (float)N_TOK);
    }
}

// ---------------- Gather: A1[row] = norm[token]*ln_g[e] + ln_b[e] ----------------
__global__ __launch_bounds__(256)
void gather_kernel(const ushort* __restrict__ norm, const float* __restrict__ ln_g,
                   const float* __restrict__ ln_b, const int* __restrict__ offs,
                   const int* __restrict__ lists, ushort* __restrict__ A1) {
    const int r = blockIdx.x;
    int e = 0;
    #pragma unroll
    for (int k = 1; k < NEXP; ++k) if (r >= offs[k]) e = k;
    const int slot = r - offs[e];
    const int token = lists[e * NMAX + slot];
    const int t4 = threadIdx.x * 4;
    uint2 nbv = *(const uint2*)(norm + (size_t)token * DMODEL + t4);
    ushort ns[4]; *(uint2*)ns = nbv;
    float4 gv = *(const float4*)(ln_g + (size_t)e * DMODEL + t4);
    float4 bv = *(const float4*)(ln_b + (size_t)e * DMODEL + t4);
    ushort ob[4] = { f2bf(bf2f(ns[0]) * gv.x + bv.x), f2bf(bf2f(ns[1]) * gv.y + bv.y),
                     f2bf(bf2f(ns[2]) * gv.z + bv.z), f2bf(bf2f(ns[3]) * gv.w + bv.w) };
    *(uint2*)(A1 + (size_t)r * DMODEL + t4) = *(uint2*)ob;
}

// ---------------- Grouped GEMM (m97 structure): A bf16 + W f32, BOTH via gl_lds ------
// W staged f32 into LDS with 16B-chunk XOR swizzle (both-sides involution), converted
// to bf16 on ds_read with v_cvt_pk_bf16_f32. Plain __syncthreads(); compiler manages
// waitcnt (m97-proven). Single-buffer 48 KB LDS -> 3 blocks/CU.
template<int KDIM, int NT, int KSPLT, bool RELU>
__global__ __launch_bounds__(256)
void moe_gemm(const ushort* __restrict__ A, const float* __restrict__ W,
              const float* __restrict__ bias, const int* __restrict__ cnt,
              const int* __restrict__ offs, ushort* __restrict__ hout,
              float* __restrict__ yout) {
    __shared__ ushort As[BM * BK];      // 16 KB bf16 A tile
    __shared__ float  Wsf[BN * BK];     // 32 KB f32 W tile
    constexpr int NOUT = NT * BN;

    const int q = (int)gridDim.x >> 3;
    const int logical = ((int)blockIdx.x & 7) * q + ((int)blockIdx.x >> 3);
    const int mt = logical & (MT_MAX - 1);
    int g = logical >> 4;
    const int kb = g & (KSPLT - 1);
    g /= KSPLT;
    const int nt = g % NT;
    const int e = g / NT;
    const int M = cnt[e];
    if (mt * BM >= M) return;
    const int base = offs[e];

    const int tid = threadIdx.x, lane = tid & 63, wave = tid >> 6;
    const int wm = (wave & 1) * 64, wn = (wave >> 1) * 64;
    const int trow = lane >> 3;
    const int scol = ((lane & 7) ^ trow) * 8;   // A: pre-swizzled source column (elems)

    const ushort* Agb = A + (size_t)(base + mt * BM) * KDIM;
    const float*  Wgb = W + ((size_t)e * NOUT + nt * BN) * KDIM;

    // W staging swizzle (16B chunks): physical chunk p of row r holds logical p^(r&7)
    const int wrow  = (lane >> 4);              // row within 4-row group
    const int wchnk = (lane & 15);              // physical chunk = lane&15

    f32x4 acc[4][4] = {};

    auto stageA = [&](int step) {
        #pragma unroll
        for (int i = 0; i < 4; ++i) {
            int c = wave * 4 + i;
            gl_lds16(Agb + (size_t)(c * 8 + trow) * KDIM + step * BK + scol, &As[c * 512]);
        }
    };
    auto stageW = [&](int step) {
        #pragma unroll
        for (int i = 0; i < 8; ++i) {
            int r0 = wave * 32 + i * 4;
            int row = r0 + wrow;
            int chunk = wchnk ^ (row & 7);      // inverse-swizzled source
            gl_lds16(Wgb + (size_t)row * KDIM + step * BK + chunk * 4, &Wsf[r0 * 64]);
        }
    };
    auto readW = [&](int ni, int kki) -> s16x8 {
        const int row = wn + ni * 16 + (lane & 15);
        const int x = row & 7;                  // == lane&7
        const int cb = kki * 8 + (lane >> 4) * 2;
        const float4 f0 = *(const float4*)&Wsf[row * 64 + ((cb ^ x) << 2)];
        const float4 f1 = *(const float4*)&Wsf[row * 64 + (((cb + 1) ^ x) << 2)];
        union { s16x8 v; __hip_bfloat162 h2[4]; } u;
        u.h2[0] = __float22bfloat162_rn(make_float2(f0.x, f0.y));
        u.h2[1] = __float22bfloat162_rn(make_float2(f0.z, f0.w));
        u.h2[2] = __float22bfloat162_rn(make_float2(f1.x, f1.y));
        u.h2[3] = __float22bfloat162_rn(make_float2(f1.z, f1.w));
        return u.v;
    };
    auto mfma_phase = [&]() {
        #pragma unroll
        for (int kki = 0; kki < 2; ++kki) {
            const int cx = (kki * 32 + (lane >> 4) * 8) ^ ((lane & 7) << 3);
            s16x8 af[4], bfv[4];
            #pragma unroll
            for (int mi = 0; mi < 4; ++mi)
                af[mi] = *(const s16x8*)&As[(wm + mi * 16 + (lane & 15)) * BK + cx];
            #pragma unroll
            for (int ni = 0; ni < 4; ++ni)
                bfv[ni] = readW(ni, kki);
            #pragma unroll
            for (int mi = 0; mi < 4; ++mi)
                #pragma unroll
                for (int ni = 0; ni < 4; ++ni)
                    acc[mi][ni] = __builtin_amdgcn_mfma_f32_16x16x32_bf16(
                        af[mi], bfv[ni], acc[mi][ni], 0, 0, 0);
        }
    };

    const int KS = KDIM / BK / KSPLT;
    const int kt0 = kb * KS;

    for (int s = 0; s < KS; ++s) {
        stageA(kt0 + s);
        stageW(kt0 + s);
        __syncthreads();                       // compiler emits vmcnt(0) drain here
        mfma_phase();
        __syncthreads();                       // protect LDS from next stage (WAR)
    }

    if (RELU) {
        #pragma unroll
        for (int ni = 0; ni < 4; ++ni) {
            const int nn = nt * BN + wn + ni * 16 + (lane & 15);
            const float bv = bias[(size_t)e * NOUT + nn];
            #pragma unroll
            for (int mi = 0; mi < 4; ++mi)
                #pragma unroll
                for (int r = 0; r < 4; ++r) {
                    const int slot = mt * BM + wm + mi * 16 + ((lane >> 4) << 2) + r;
                    if (slot < M)
                        hout[(size_t)(base + slot) * NOUT + nn] =
                            f2bf(fmaxf(acc[mi][ni][r] + bv, 0.f));
                }
        }
    } else {
        #pragma unroll
        for (int ni = 0; ni < 4; ++ni) {
            const int nn = nt * BN + wn + ni * 16 + (lane & 15);
            #pragma unroll
            for (int mi = 0; mi < 4; ++mi)
                #pragma unroll
                for (int r = 0; r < 4; ++r) {
                    const int slot = mt * BM + wm + mi * 16 + ((lane >> 4) << 2) + r;
                    if (slot < M)
                        yout[((size_t)kb * ROWS + base + slot) * NOUT + nn] = acc[mi][ni][r];
                }
        }
    }
}

// ---------------- Combine: out[n] = sum_e g_e * (sum_kb ypart + b2[e] + x[n]) -------
__global__ __launch_bounds__(256)
void combine_kernel(const float* __restrict__ ypart, const float* __restrict__ b2,
                    const float* __restrict__ x, const int* __restrict__ offs,
                    const int4* __restrict__ info, const float2* __restrict__ gpair,
                    float* __restrict__ out) {
    const int n = blockIdx.x, d = threadIdx.x * 4;
    const int4 ii = info[n];
    const float2 g = gpair[n];
    const int r1 = offs[ii.x] + ii.y, r2 = offs[ii.z] + ii.w;
    f32x4 y1 = {}, y2 = {};
    #pragma unroll
    for (int kb = 0; kb < KSPL; ++kb) {
        y1 += *(const f32x4*)(ypart + ((size_t)kb * ROWS + r1) * DMODEL + d);
        y2 += *(const f32x4*)(ypart + ((size_t)kb * ROWS + r2) * DMODEL + d);
    }
    const f32x4 b21 = *(const f32x4*)(b2 + (size_t)ii.x * DMODEL + d);
    const f32x4 b22 = *(const f32x4*)(b2 + (size_t)ii.z * DMODEL + d);
    const f32x4 xv  = *(const f32x4*)(x + (size_t)n * DMODEL + d);
    f32x4 o = g.x * (y1 + b21 + xv) + g.y * (y2 + b22 + xv);
    *(f32x4*)(out + (size_t)n * DMODEL + d) = o;
}

extern "C" void kernel_launch(void* const* d_in, const int* in_sizes, int n_in,
                              void* d_out, int out_size, void* d_ws, size_t ws_size,
                              hipStream_t stream) {
    const float* x      = (const float*)d_in[0];
    const float* gate_w = (const float*)d_in[1];
    const float* ln_g   = (const float*)d_in[2];
    const float* ln_b   = (const float*)d_in[3];
    const float* w1     = (const float*)d_in[4];
    const float* b1     = (const float*)d_in[5];
    const float* w2     = (const float*)d_in[6];
    const float* b2     = (const float*)d_in[7];
    float* out = (float*)d_out;

    char* w = (char*)d_ws;
    int*    cnt    = (int*)(w + 0);
    int*    offs   = (int*)(w + 64);
    int*    lists  = (int*)(w + 1024);            // 64 KB
    float*  scores = (float*)(w + 66560);         // 64 KB
    int4*   info   = (int4*)(w + 132096);         // 32 KB
    float2* gpair  = (float2*)(w + 164864);       // 16 KB
    ushort* norm   = (ushort*)(w + 181248);       // 4 MB
    ushort* A1     = (ushort*)(w + 4375552);      // 8.4 MB
    ushort* h      = (ushort*)(w + 12764160);     // 33.6 MB
    float*  ypart  = (float*)(w + 46318592);      // 64 MB (KSPL x ROWS x D f32)

    hipMemsetAsync(cnt, 0, 64, stream);

    router_kernel<<<N_TOK, 256, 0, stream>>>(x, gate_w, norm, scores, cnt, lists, info, gpair);
    prep_kernel<<<1, 256, 0, stream>>>(scores, cnt, offs, out + (size_t)N_TOK * DMODEL);
    gather_kernel<<<ROWS, 256, 0, stream>>>(norm, ln_g, ln_b, offs, lists, A1);
    moe_gemm<DMODEL, FFDIM / BN, 1, true><<<(FFDIM / BN) * MT_MAX * NEXP, 256, 0, stream>>>(
        A1, w1, b1, cnt, offs, h, nullptr);
    moe_gemm<FFDIM, DMODEL / BN, KSPL, false><<<(DMODEL / BN) * MT_MAX * NEXP * KSPL, 256, 0, stream>>>(
        h, w2, nullptr, cnt, offs, nullptr, ypart);
    combine_kernel<<<N_TOK, 256, 0, stream>>>(ypart, b2, x, offs, info, gpair, out);
}

// Round 7
// 258.259 us; speedup vs baseline: 2.4816x; 1.4135x over previous
//
#include <hip/hip_runtime.h>
#include <hip/hip_bf16.h>

#define N_TOK 2048
#define DMODEL 1024
#define NEXP 8
#define FFDIM 4096
#define NMAX 2048
#define PADROWS 5120   // 4096 + 8*127 rounded up
#define TMAX 40        // max row-tiles: 4096/128 + 8

#define BM 128
#define BN 128
#define BK 64
#define KSPL 4

typedef __attribute__((ext_vector_type(8))) short s16x8;
typedef __attribute__((ext_vector_type(4))) float f32x4;

__device__ __forceinline__ float bf2f(ushort u) {
    union { uint i; float f; } x; x.i = ((uint)u) << 16; return x.f;
}
__device__ __forceinline__ ushort f2bf(float f) {
    union { float f; uint i; } x; x.f = f;
    uint r = x.i + 0x7fffu + ((x.i >> 16) & 1u);
    return (ushort)(r >> 16);
}

__device__ __forceinline__ void gl_lds16(const void* g, void* l) {
    __builtin_amdgcn_global_load_lds(
        (const __attribute__((address_space(1))) unsigned int*)g,
        (__attribute__((address_space(3))) unsigned int*)l, 16, 0, 0);
}

__device__ __forceinline__ float block_sum(float v, float* s4) {
    #pragma unroll
    for (int off = 32; off; off >>= 1) v += __shfl_down(v, off);
    __syncthreads();
    if ((threadIdx.x & 63) == 0) s4[threadIdx.x >> 6] = v;
    __syncthreads();
    return s4[0] + s4[1] + s4[2] + s4[3];
}

// ---------------- Router ----------------
__global__ __launch_bounds__(256)
void router_kernel(const float* __restrict__ x, const float* __restrict__ gate_w,
                   ushort* __restrict__ norm, float* __restrict__ scores,
                   int* __restrict__ cnt, int* __restrict__ lists,
                   int4* __restrict__ info, float2* __restrict__ gpair) {
    __shared__ float s4[4];
    const int n = blockIdx.x, tid = threadIdx.x;
    const float* xr = x + (size_t)n * DMODEL;
    float4 v = *(const float4*)(xr + tid * 4);

    float tot = block_sum(v.x + v.y + v.z + v.w, s4);
    float mu = tot * (1.0f / DMODEL);
    float d0 = v.x - mu, d1 = v.y - mu, d2 = v.z - mu, d3 = v.w - mu;
    float var = block_sum(d0 * d0 + d1 * d1 + d2 * d2 + d3 * d3, s4) * (1.0f / DMODEL);
    float rstd = rsqrtf(var + 1e-6f);

    ushort nb[4] = { f2bf(d0 * rstd), f2bf(d1 * rstd), f2bf(d2 * rstd), f2bf(d3 * rstd) };
    *(uint2*)(norm + (size_t)n * DMODEL + tid * 4) = *(uint2*)nb;

    float lg[NEXP];
    #pragma unroll
    for (int e = 0; e < NEXP; ++e) {
        float4 g = *(const float4*)(gate_w + (size_t)e * DMODEL + tid * 4);
        lg[e] = v.x * g.x + v.y * g.y + v.z * g.z + v.w * g.w;
    }
    #pragma unroll
    for (int e = 0; e < NEXP; ++e) lg[e] = block_sum(lg[e], s4);

    if (tid == 0) {
        float m = lg[0];
        #pragma unroll
        for (int e = 1; e < NEXP; ++e) m = fmaxf(m, lg[e]);
        float ex[NEXP], Z = 0.f;
        #pragma unroll
        for (int e = 0; e < NEXP; ++e) { ex[e] = expf(lg[e] - m); Z += ex[e]; }
        float inv = 1.0f / Z;
        float sc[NEXP];
        #pragma unroll
        for (int e = 0; e < NEXP; ++e) { sc[e] = ex[e] * inv; scores[n * NEXP + e] = sc[e]; }
        int i1 = 0;
        #pragma unroll
        for (int e = 1; e < NEXP; ++e) if (sc[e] > sc[i1]) i1 = e;
        int i2 = (i1 == 0) ? 1 : 0;
        #pragma unroll
        for (int e = 0; e < NEXP; ++e) if (e != i1 && sc[e] > sc[i2]) i2 = e;
        int s1 = atomicAdd(&cnt[i1], 1);
        lists[i1 * NMAX + s1] = n;
        int s2 = atomicAdd(&cnt[i2], 1);
        lists[i2 * NMAX + s2] = n;
        info[n] = make_int4(i1, s1, i2, s2);
        gpair[n] = make_float2(sc[i1], sc[i2]);
    }
}

// ------- Prep: aux loss + PADDED (128-aligned) offsets + row-tile map -------
__global__ __launch_bounds__(256)
void prep_kernel(const float* __restrict__ scores, const int* __restrict__ cnt,
                 int* __restrict__ offs_pad, int* __restrict__ ntiles,
                 int4* __restrict__ tilemap, float* __restrict__ aux_out) {
    __shared__ float s4[4];
    __shared__ float imp[NEXP];
    float part[NEXP] = {};
    for (int i = threadIdx.x; i < N_TOK; i += 256) {
        #pragma unroll
        for (int e = 0; e < NEXP; ++e) part[e] += scores[i * NEXP + e];
    }
    #pragma unroll
    for (int e = 0; e < NEXP; ++e) {
        float s = block_sum(part[e], s4);
        if (threadIdx.x == 0) imp[e] = s;
    }
    __syncthreads();
    if (threadIdx.x == 0) {
        float aux = 0.f; int pad = 0, idx = 0;
        #pragma unroll
        for (int e = 0; e < NEXP; ++e) {
            aux += imp[e] * (float)cnt[e];
            offs_pad[e] = pad;
            int tiles = (cnt[e] + BM - 1) / BM;
            for (int t = 0; t < tiles; ++t)
                tilemap[idx++] = make_int4(e, pad + t * BM, 0, 0);
            pad += tiles * BM;
        }
        offs_pad[NEXP] = pad;
        ntiles[0] = idx;
        aux_out[0] = aux * (float)NEXP / ((float)N_TOK * (float)N_TOK);
    }
}

// ------- Gather into padded grouped layout; zero pad rows -------
__global__ __launch_bounds__(256)
void gather_kernel(const ushort* __restrict__ norm, const float* __restrict__ ln_g,
                   const float* __restrict__ ln_b, const int* __restrict__ offs_pad,
                   const int* __restrict__ cnt, const int* __restrict__ lists,
                   ushort* __restrict__ A1) {
    const int r = blockIdx.x;
    int e = 0;
    #pragma unroll
    for (int k = 1; k < NEXP; ++k) if (r >= offs_pad[k]) e = k;
    const int slot = r - offs_pad[e];
    const int t4 = threadIdx.x * 4;
    if (slot >= cnt[e]) {   // pad row -> zeros
        ushort z[4] = {};
        *(uint2*)(A1 + (size_t)r * DMODEL + t4) = *(uint2*)z;
        return;
    }
    const int token = lists[e * NMAX + slot];
    uint2 nbv = *(const uint2*)(norm + (size_t)token * DMODEL + t4);
    ushort ns[4]; *(uint2*)ns = nbv;
    float4 gv = *(const float4*)(ln_g + (size_t)e * DMODEL + t4);
    float4 bv = *(const float4*)(ln_b + (size_t)e * DMODEL + t4);
    ushort ob[4] = { f2bf(bf2f(ns[0]) * gv.x + bv.x), f2bf(bf2f(ns[1]) * gv.y + bv.y),
                     f2bf(bf2f(ns[2]) * gv.z + bv.z), f2bf(bf2f(ns[3]) * gv.w + bv.w) };
    *(uint2*)(A1 + (size_t)r * DMODEL + t4) = *(uint2*)ob;
}

// ------- Grouped GEMM (tilemap grid = all-active): A bf16 + W f32 via gl_lds -------
// Inner loop identical to R6 (verified). Grid has NO dead blocks: bt indexes real
// row-tiles; pad rows are zeros so no epilogue bounds checks needed.
template<int KDIM, int NT, int KSPLT, bool RELU>
__global__ __launch_bounds__(256, 3)
void moe_gemm(const ushort* __restrict__ A, const float* __restrict__ W,
              const float* __restrict__ bias, const int* __restrict__ ntiles,
              const int4* __restrict__ tilemap, ushort* __restrict__ hout,
              float* __restrict__ yout) {
    __shared__ ushort As[BM * BK];      // 16 KB bf16 A tile
    __shared__ float  Wsf[BN * BK];     // 32 KB f32 W tile
    constexpr int NOUT = NT * BN;

    const int q = (int)gridDim.x >> 3;
    const int logical = ((int)blockIdx.x & 7) * q + ((int)blockIdx.x >> 3);
    const int bt = logical % TMAX;
    int g = logical / TMAX;
    if (bt >= ntiles[0]) return;
    const int nt = g % NT;
    const int kb = g / NT;              // 0 when KSPLT==1
    const int4 tm = tilemap[bt];
    const int e = tm.x, row0 = tm.y;

    const int tid = threadIdx.x, lane = tid & 63, wave = tid >> 6;
    const int wm = (wave & 1) * 64, wn = (wave >> 1) * 64;
    const int trow = lane >> 3;
    const int scol = ((lane & 7) ^ trow) * 8;   // A: pre-swizzled source column

    const ushort* Agb = A + (size_t)row0 * KDIM;
    const float*  Wgb = W + ((size_t)e * NOUT + nt * BN) * KDIM;

    const int wrow  = (lane >> 4);
    const int wchnk = (lane & 15);

    f32x4 acc[4][4] = {};

    auto stageA = [&](int step) {
        #pragma unroll
        for (int i = 0; i < 4; ++i) {
            int c = wave * 4 + i;
            gl_lds16(Agb + (size_t)(c * 8 + trow) * KDIM + step * BK + scol, &As[c * 512]);
        }
    };
    auto stageW = [&](int step) {
        #pragma unroll
        for (int i = 0; i < 8; ++i) {
            int r0 = wave * 32 + i * 4;
            int row = r0 + wrow;
            int chunk = wchnk ^ (row & 7);
            gl_lds16(Wgb + (size_t)row * KDIM + step * BK + chunk * 4, &Wsf[r0 * 64]);
        }
    };
    auto readW = [&](int ni, int kki) -> s16x8 {
        const int row = wn + ni * 16 + (lane & 15);
        const int x = row & 7;
        const int cb = kki * 8 + (lane >> 4) * 2;
        const float4 f0 = *(const float4*)&Wsf[row * 64 + ((cb ^ x) << 2)];
        const float4 f1 = *(const float4*)&Wsf[row * 64 + (((cb + 1) ^ x) << 2)];
        union { s16x8 v; __hip_bfloat162 h2[4]; } u;
        u.h2[0] = __float22bfloat162_rn(make_float2(f0.x, f0.y));
        u.h2[1] = __float22bfloat162_rn(make_float2(f0.z, f0.w));
        u.h2[2] = __float22bfloat162_rn(make_float2(f1.x, f1.y));
        u.h2[3] = __float22bfloat162_rn(make_float2(f1.z, f1.w));
        return u.v;
    };
    auto mfma_phase = [&]() {
        #pragma unroll
        for (int kki = 0; kki < 2; ++kki) {
            const int cx = (kki * 32 + (lane >> 4) * 8) ^ ((lane & 7) << 3);
            s16x8 af[4], bfv[4];
            #pragma unroll
            for (int mi = 0; mi < 4; ++mi)
                af[mi] = *(const s16x8*)&As[(wm + mi * 16 + (lane & 15)) * BK + cx];
            #pragma unroll
            for (int ni = 0; ni < 4; ++ni)
                bfv[ni] = readW(ni, kki);
            #pragma unroll
            for (int mi = 0; mi < 4; ++mi)
                #pragma unroll
                for (int ni = 0; ni < 4; ++ni)
                    acc[mi][ni] = __builtin_amdgcn_mfma_f32_16x16x32_bf16(
                        af[mi], bfv[ni], acc[mi][ni], 0, 0, 0);
        }
    };

    const int KS = KDIM / BK / KSPLT;
    const int kt0 = kb * KS;

    for (int s = 0; s < KS; ++s) {
        stageA(kt0 + s);
        stageW(kt0 + s);
        __syncthreads();
        mfma_phase();
        __syncthreads();
    }

    if (RELU) {
        #pragma unroll
        for (int ni = 0; ni < 4; ++ni) {
            const int nn = nt * BN + wn + ni * 16 + (lane & 15);
            const float bv = bias[(size_t)e * NOUT + nn];
            #pragma unroll
            for (int mi = 0; mi < 4; ++mi)
                #pragma unroll
                for (int r = 0; r < 4; ++r) {
                    const int sl = wm + mi * 16 + ((lane >> 4) << 2) + r;
                    hout[(size_t)(row0 + sl) * NOUT + nn] =
                        f2bf(fmaxf(acc[mi][ni][r] + bv, 0.f));
                }
        }
    } else {
        #pragma unroll
        for (int ni = 0; ni < 4; ++ni) {
            const int nn = nt * BN + wn + ni * 16 + (lane & 15);
            #pragma unroll
            for (int mi = 0; mi < 4; ++mi)
                #pragma unroll
                for (int r = 0; r < 4; ++r) {
                    const int sl = wm + mi * 16 + ((lane >> 4) << 2) + r;
                    yout[((size_t)kb * PADROWS + row0 + sl) * NOUT + nn] = acc[mi][ni][r];
                }
        }
    }
}

// ------- Combine: out[n] = sum_e g_e * (sum_kb ypart + b2[e] + x[n]) -------
__global__ __launch_bounds__(256)
void combine_kernel(const float* __restrict__ ypart, const float* __restrict__ b2,
                    const float* __restrict__ x, const int* __restrict__ offs_pad,
                    const int4* __restrict__ info, const float2* __restrict__ gpair,
                    float* __restrict__ out) {
    const int n = blockIdx.x, d = threadIdx.x * 4;
    const int4 ii = info[n];
    const float2 g = gpair[n];
    const int r1 = offs_pad[ii.x] + ii.y, r2 = offs_pad[ii.z] + ii.w;
    f32x4 y1 = {}, y2 = {};
    #pragma unroll
    for (int kb = 0; kb < KSPL; ++kb) {
        y1 += *(const f32x4*)(ypart + ((size_t)kb * PADROWS + r1) * DMODEL + d);
        y2 += *(const f32x4*)(ypart + ((size_t)kb * PADROWS + r2) * DMODEL + d);
    }
    const f32x4 b21 = *(const f32x4*)(b2 + (size_t)ii.x * DMODEL + d);
    const f32x4 b22 = *(const f32x4*)(b2 + (size_t)ii.z * DMODEL + d);
    const f32x4 xv  = *(const f32x4*)(x + (size_t)n * DMODEL + d);
    f32x4 o = g.x * (y1 + b21 + xv) + g.y * (y2 + b22 + xv);
    *(f32x4*)(out + (size_t)n * DMODEL + d) = o;
}

extern "C" void kernel_launch(void* const* d_in, const int* in_sizes, int n_in,
                              void* d_out, int out_size, void* d_ws, size_t ws_size,
                              hipStream_t stream) {
    const float* x      = (const float*)d_in[0];
    const float* gate_w = (const float*)d_in[1];
    const float* ln_g   = (const float*)d_in[2];
    const float* ln_b   = (const float*)d_in[3];
    const float* w1     = (const float*)d_in[4];
    const float* b1     = (const float*)d_in[5];
    const float* w2     = (const float*)d_in[6];
    const float* b2     = (const float*)d_in[7];
    float* out = (float*)d_out;

    char* w = (char*)d_ws;
    int*    cnt      = (int*)(w + 0);
    int*    offs_pad = (int*)(w + 64);
    int*    ntiles   = (int*)(w + 128);
    int4*   tilemap  = (int4*)(w + 192);          // 40*16 = 640 B
    int*    lists    = (int*)(w + 1024);          // 64 KB
    float*  scores   = (float*)(w + 66560);       // 64 KB
    int4*   info     = (int4*)(w + 132096);       // 32 KB
    float2* gpair    = (float2*)(w + 164864);     // 16 KB
    ushort* norm     = (ushort*)(w + 181248);     // 4 MB
    ushort* A1       = (ushort*)(w + 4375552);    // PADROWS x D bf16 = 10.5 MB
    ushort* h        = (ushort*)(w + 14861312);   // PADROWS x FF bf16 = 41.9 MB
    float*  ypart    = (float*)(w + 56804352);    // KSPL x PADROWS x D f32 = 84 MB

    hipMemsetAsync(cnt, 0, 64, stream);

    router_kernel<<<N_TOK, 256, 0, stream>>>(x, gate_w, norm, scores, cnt, lists, info, gpair);
    prep_kernel<<<1, 256, 0, stream>>>(scores, cnt, offs_pad, ntiles, tilemap,
                                       out + (size_t)N_TOK * DMODEL);
    gather_kernel<<<PADROWS, 256, 0, stream>>>(norm, ln_g, ln_b, offs_pad, cnt, lists, A1);
    moe_gemm<DMODEL, FFDIM / BN, 1, true><<<TMAX * (FFDIM / BN), 256, 0, stream>>>(
        A1, w1, b1, ntiles, tilemap, h, nullptr);
    moe_gemm<FFDIM, DMODEL / BN, KSPL, false><<<TMAX * (DMODEL / BN) * KSPL, 256, 0, stream>>>(
        h, w2, nullptr, ntiles, tilemap, nullptr, ypart);
    combine_kernel<<<N_TOK, 256, 0, stream>>>(ypart, b2, x, offs_pad, info, gpair, out);
}